// Round 1
// baseline (821.579 us; speedup 1.0000x reference)
//
#include <hip/hip_runtime.h>
#include <cstdint>
#include <cstddef>

// Problem constants (from setup_inputs)
#define T_TOK 8192
#define HDIM  2048
#define NEXP  8
#define IDIM  1024
#define CAP   17408   // 16384 assignments + 8*127 padding, rounded to 128
#define NTILE (CAP / 128)   // 136 padded slot-tiles max
#define LTOK  16            // tokens per logits block

typedef __attribute__((ext_vector_type(8))) __bf16 bf16x8;
typedef __attribute__((ext_vector_type(4))) __bf16 bf16x4;
typedef __attribute__((ext_vector_type(4))) float  f32x4;

// async global->LDS, 16B/lane. LDS dest = wave-uniform base + lane*16.
#define GLDS16(g, l)                                                        \
  __builtin_amdgcn_global_load_lds(                                         \
      (__attribute__((address_space(1))) void*)(g),                         \
      (__attribute__((address_space(3))) void*)(l), 16, 0, 0)

// ---------------------------------------------------------------------------
// fp32 -> bf16 bulk convert (weights)
__global__ __launch_bounds__(256) void cvt_k(const float* __restrict__ src,
                                             __bf16* __restrict__ dst, int n4) {
  int i = blockIdx.x * blockDim.x + threadIdx.x;
  int stride = gridDim.x * blockDim.x;
  for (; i < n4; i += stride) {
    float4 v = ((const float4*)src)[i];
    bf16x4 b;
    b[0] = (__bf16)v.x; b[1] = (__bf16)v.y; b[2] = (__bf16)v.z; b[3] = (__bf16)v.w;
    ((bf16x4*)dst)[i] = b;
  }
}

// ---------------------------------------------------------------------------
// Logits + top-2: wg staged in LDS (64 KB fp32), one wave per token (4 tokens
// sequential per wave), fp64 accumulation, NO global atomics. Fuses the
// fp32->bf16 cast of x.
__global__ __launch_bounds__(256) void logits_k(
    const float* __restrict__ x, const float* __restrict__ wg,
    __bf16* __restrict__ xb, int* __restrict__ tok_idx,
    float* __restrict__ tok_w) {
  __shared__ float wgs[NEXP * HDIM];   // 64 KB
  {
    const float4* wg4 = (const float4*)wg;
    float4* wgs4 = (float4*)wgs;
    for (int i = threadIdx.x; i < NEXP * HDIM / 4; i += 256) wgs4[i] = wg4[i];
  }
  __syncthreads();

  const int wid  = threadIdx.x >> 6;
  const int lane = threadIdx.x & 63;

  for (int ti = 0; ti < LTOK / 4; ++ti) {
    const int t = blockIdx.x * LTOK + wid * (LTOK / 4) + ti;
    const float4* x4 = (const float4*)(x + (size_t)t * HDIM);
    bf16x4* xb4 = (bf16x4*)(xb + (size_t)t * HDIM);

    double acc[NEXP];
#pragma unroll
    for (int e = 0; e < NEXP; ++e) acc[e] = 0.0;

#pragma unroll
    for (int j = 0; j < 8; ++j) {
      int idx = j * 64 + lane;          // float4 index (512 per row)
      float4 xv = x4[idx];
      bf16x4 b;
      b[0] = (__bf16)xv.x; b[1] = (__bf16)xv.y; b[2] = (__bf16)xv.z; b[3] = (__bf16)xv.w;
      xb4[idx] = b;
#pragma unroll
      for (int e = 0; e < NEXP; ++e) {
        float4 wv = ((const float4*)(wgs + e * HDIM))[idx];
        acc[e] += (double)xv.x * wv.x + (double)xv.y * wv.y +
                  (double)xv.z * wv.z + (double)xv.w * wv.w;
      }
    }
#pragma unroll
    for (int off = 32; off > 0; off >>= 1)
#pragma unroll
      for (int e = 0; e < NEXP; ++e) acc[e] += __shfl_xor(acc[e], off, 64);

    if (lane == 0) {
      int i0 = 0; double m0 = acc[0];
      for (int e = 1; e < NEXP; ++e) if (acc[e] > m0) { m0 = acc[e]; i0 = e; }
      int i1 = -1; double m1 = -1e300;
      for (int e = 0; e < NEXP; ++e)
        if (e != i0 && acc[e] > m1) { m1 = acc[e]; i1 = e; }
      double p0 = 1.0 / (1.0 + exp(m1 - m0));   // renorm: denominators cancel
      tok_idx[t * 2 + 0] = i0;  tok_idx[t * 2 + 1] = i1;
      tok_w[t * 2 + 0] = (float)p0;
      tok_w[t * 2 + 1] = (float)(1.0 - p0);
    }
  }
}

// ---------------------------------------------------------------------------
// LDS-aggregated histogram: 32 blocks x 256 tokens -> 8 global atomics/block
__global__ __launch_bounds__(256) void hist_k(const int* __restrict__ tok_idx,
                                              int* __restrict__ counts) {
  __shared__ int h[NEXP];
  if (threadIdx.x < NEXP) h[threadIdx.x] = 0;
  __syncthreads();
  int t = blockIdx.x * blockDim.x + threadIdx.x;
  atomicAdd(&h[tok_idx[t * 2 + 0]], 1);
  atomicAdd(&h[tok_idx[t * 2 + 1]], 1);
  __syncthreads();
  if (threadIdx.x < NEXP) atomicAdd(&counts[threadIdx.x], h[threadIdx.x]);
}

// ---------------------------------------------------------------------------
// Padded exclusive scan of counts. offp[NEXP] = total padded slots.
__global__ void offsets_k(const int* __restrict__ counts, int* __restrict__ offp,
                          int* __restrict__ ctr2) {
  if (threadIdx.x == 0) {
    int off = 0;
    for (int e = 0; e < NEXP; ++e) { offp[e] = off; off += (counts[e] + 127) & ~127; }
    offp[NEXP] = off;
  }
  if (threadIdx.x < NEXP) ctr2[threadIdx.x] = 0;
}

// ---------------------------------------------------------------------------
// Bucket scatter with LDS ranking: per block, local ranks via LDS atomics,
// one chunk-reservation global atomic per expert per block (8 x 32 total).
__global__ __launch_bounds__(256) void assign_k(
    const int* __restrict__ tok_idx, const float* __restrict__ tok_w,
    const int* __restrict__ offp, int* __restrict__ ctr2,
    int* __restrict__ btok, float* __restrict__ bw, int* __restrict__ pos_of) {
  __shared__ int lcnt[NEXP], lbase[NEXP];
  if (threadIdx.x < NEXP) lcnt[threadIdx.x] = 0;
  __syncthreads();
  const int t  = blockIdx.x * blockDim.x + threadIdx.x;
  const int e0 = tok_idx[t * 2 + 0];
  const int e1 = tok_idx[t * 2 + 1];
  const int r0 = atomicAdd(&lcnt[e0], 1);
  const int r1 = atomicAdd(&lcnt[e1], 1);
  __syncthreads();
  if (threadIdx.x < NEXP)
    lbase[threadIdx.x] = atomicAdd(&ctr2[threadIdx.x], lcnt[threadIdx.x]);
  __syncthreads();
  int p0 = offp[e0] + lbase[e0] + r0;
  int p1 = offp[e1] + lbase[e1] + r1;
  btok[p0] = t;  bw[p0] = tok_w[t * 2 + 0];  pos_of[t * 2 + 0] = p0;
  btok[p1] = t;  bw[p1] = tok_w[t * 2 + 1];  pos_of[t * 2 + 1] = p1;
}

// ---------------------------------------------------------------------------
// Map a padded-slot tile (128 rows) to its expert. Returns -1 if out of range.
__device__ __forceinline__ int tile_expert(const int* offp, int slot0) {
  if (slot0 >= offp[NEXP]) return -1;
  int e = 0;
#pragma unroll
  for (int i = 1; i < NEXP; ++i) if (offp[i] <= slot0) e = i;
  return e;
}

// ---------------------------------------------------------------------------
// GEMM1 (fused): gathered X [128 x K2048] x (w1,w3 tiles [128 x K]) -> dual
// accumulators; epilogue h = silu(g)*u in registers.
// v2: double-buffered LDS + 2-phase pipeline. Prefetch of tile kt+1 is
// issued BEFORE the compute of tile kt, so the vmcnt(0) drain at the single
// per-iteration barrier lands after ~300 cycles of MFMA instead of exposing
// the full global->LDS latency every K-step (old version: stage -> drain ->
// compute, MfmaUtil 25%).
__global__ __launch_bounds__(256, 2) void gemm1_k(
    const __bf16* __restrict__ xb, const __bf16* __restrict__ w1b,
    const __bf16* __restrict__ w3b, __bf16* __restrict__ h,
    const int* __restrict__ btok, const int* __restrict__ counts,
    const int* __restrict__ offp) {
  const int mt    = blockIdx.y;
  const int slot0 = mt * 128;
  const int e     = tile_expert(offp, slot0);
  if (e < 0) return;
  const int cnt  = counts[e];
  const int base = offp[e];
  const int mrow = slot0 - base;
  const int it   = blockIdx.x;            // 128 i-values per block

  __shared__ __align__(16) __bf16 As [2][128 * 32];   // 16 KB
  __shared__ __align__(16) __bf16 B1s[2][128 * 32];   // 16 KB
  __shared__ __align__(16) __bf16 B3s[2][128 * 32];   // 16 KB

  const int tid  = threadIdx.x;
  const int lane = tid & 63;
  const int wid  = tid >> 6;
  const int wy   = wid >> 1, wx = wid & 1;

  const int r0 = tid >> 2;
  const int c8 = (tid & 3) * 8;
  int ma = mrow + r0, mb = ma + 64;
  int toka = btok[base + (ma < cnt ? ma : cnt - 1)];
  int tokb = btok[base + (mb < cnt ? mb : cnt - 1)];
  const __bf16* pA0  = xb + (size_t)toka * HDIM + c8;
  const __bf16* pA1  = xb + (size_t)tokb * HDIM + c8;
  const __bf16* pB1a = w1b + ((size_t)e * IDIM + it * 128 + r0) * HDIM + c8;
  const __bf16* pB1b = pB1a + (size_t)64 * HDIM;
  const __bf16* pB3a = w3b + ((size_t)e * IDIM + it * 128 + r0) * HDIM + c8;
  const __bf16* pB3b = pB3a + (size_t)64 * HDIM;

  const int wbase = wid * 512;

  f32x4 accg[4][4] = {};
  f32x4 accu[4][4] = {};
  const int frow = lane & 15;
  const int fk   = (lane >> 4) * 8;

#define G1_STAGE(b)                                                          \
  do {                                                                       \
    GLDS16(pA0,  As[b] + wbase);  GLDS16(pA1,  As[b] + 2048 + wbase);        \
    GLDS16(pB1a, B1s[b] + wbase); GLDS16(pB1b, B1s[b] + 2048 + wbase);       \
    GLDS16(pB3a, B3s[b] + wbase); GLDS16(pB3b, B3s[b] + 2048 + wbase);       \
    pA0 += 32; pA1 += 32; pB1a += 32; pB1b += 32; pB3a += 32; pB3b += 32;    \
  } while (0)

#define G1_COMPUTE(b)                                                        \
  do {                                                                       \
    bf16x8 af[4], bf1[4], bf3[4];                                            \
    _Pragma("unroll")                                                        \
    for (int mf = 0; mf < 4; ++mf)                                           \
      af[mf] = *(const bf16x8*)&As[b][(wy * 64 + mf * 16 + frow) * 32 + fk]; \
    _Pragma("unroll")                                                        \
    for (int nf = 0; nf < 4; ++nf) {                                         \
      bf1[nf] = *(const bf16x8*)&B1s[b][(wx * 64 + nf * 16 + frow) * 32 + fk]; \
      bf3[nf] = *(const bf16x8*)&B3s[b][(wx * 64 + nf * 16 + frow) * 32 + fk]; \
    }                                                                        \
    _Pragma("unroll")                                                        \
    for (int mf = 0; mf < 4; ++mf)                                           \
      _Pragma("unroll")                                                      \
      for (int nf = 0; nf < 4; ++nf) {                                       \
        accg[mf][nf] = __builtin_amdgcn_mfma_f32_16x16x32_bf16(af[mf], bf1[nf], accg[mf][nf], 0, 0, 0); \
        accu[mf][nf] = __builtin_amdgcn_mfma_f32_16x16x32_bf16(af[mf], bf3[nf], accu[mf][nf], 0, 0, 0); \
      }                                                                      \
  } while (0)

  // HDIM/32 = 64 K-tiles. tile k lives in buf[k&1].
  G1_STAGE(0);                 // tile 0
  __syncthreads();
#pragma unroll 1
  for (int t = 0; t < 31; ++t) {
    G1_STAGE(1);               // tile 2t+1
    G1_COMPUTE(0);             // tile 2t
    __syncthreads();
    G1_STAGE(0);               // tile 2t+2
    G1_COMPUTE(1);             // tile 2t+1
    __syncthreads();
  }
  G1_STAGE(1);                 // tile 63
  G1_COMPUTE(0);               // tile 62
  __syncthreads();
  G1_COMPUTE(1);               // tile 63

#undef G1_STAGE
#undef G1_COMPUTE

  const int i0c = it * 128 + wx * 64;
#pragma unroll
  for (int mf = 0; mf < 4; ++mf) {
    const int sbase = slot0 + wy * 64 + mf * 16 + (lane >> 4) * 4;
#pragma unroll
    for (int nf = 0; nf < 4; ++nf) {
      const int ic = i0c + nf * 16 + (lane & 15);
#pragma unroll
      for (int ri = 0; ri < 4; ++ri) {
        int s = sbase + ri;
        if (s - base < cnt) {
          float g = accg[mf][nf][ri];
          float u = accu[mf][nf][ri];
          float sv = g / (1.0f + __expf(-g)) * u;
          h[(size_t)s * IDIM + ic] = (__bf16)sv;
        }
      }
    }
  }
}

// ---------------------------------------------------------------------------
// GEMM2: h [128 x K1024] x w2 tile [128 x K1024] -> y[slot] = w * acc (bf16)
// v2: same double-buffered 2-phase pipeline as gemm1.
__global__ __launch_bounds__(256) void gemm2_k(
    const __bf16* __restrict__ h, const __bf16* __restrict__ w2b,
    __bf16* __restrict__ y, const float* __restrict__ bw,
    const int* __restrict__ offp) {
  const int mt    = blockIdx.y;
  const int slot0 = mt * 128;
  const int e     = tile_expert(offp, slot0);
  if (e < 0) return;
  const int nt = blockIdx.x;     // 128 H-cols per block

  __shared__ __align__(16) __bf16 As[2][128 * 32];   // 16 KB
  __shared__ __align__(16) __bf16 Bs[2][128 * 32];   // 16 KB

  const int tid  = threadIdx.x;
  const int lane = tid & 63;
  const int wid  = tid >> 6;
  const int wy   = wid >> 1, wx = wid & 1;

  const int r0 = tid >> 2;
  const int c8 = (tid & 3) * 8;
  const __bf16* pA0 = h + ((size_t)slot0 + r0) * IDIM + c8;
  const __bf16* pA1 = pA0 + (size_t)64 * IDIM;
  const __bf16* pB0 = w2b + ((size_t)e * HDIM + nt * 128 + r0) * IDIM + c8;
  const __bf16* pB1 = pB0 + (size_t)64 * IDIM;

  const int wbase = wid * 512;

  f32x4 acc[4][4] = {};
  const int frow = lane & 15;
  const int fk   = (lane >> 4) * 8;

#define G2_STAGE(b)                                                          \
  do {                                                                       \
    GLDS16(pA0, As[b] + wbase); GLDS16(pA1, As[b] + 2048 + wbase);           \
    GLDS16(pB0, Bs[b] + wbase); GLDS16(pB1, Bs[b] + 2048 + wbase);           \
    pA0 += 32; pA1 += 32; pB0 += 32; pB1 += 32;                              \
  } while (0)

#define G2_COMPUTE(b)                                                        \
  do {                                                                       \
    bf16x8 af[4], bf[4];                                                     \
    _Pragma("unroll")                                                        \
    for (int mf = 0; mf < 4; ++mf)                                           \
      af[mf] = *(const bf16x8*)&As[b][(wy * 64 + mf * 16 + frow) * 32 + fk]; \
    _Pragma("unroll")                                                        \
    for (int nf = 0; nf < 4; ++nf)                                           \
      bf[nf] = *(const bf16x8*)&Bs[b][(wx * 64 + nf * 16 + frow) * 32 + fk]; \
    _Pragma("unroll")                                                        \
    for (int mf = 0; mf < 4; ++mf)                                           \
      _Pragma("unroll")                                                      \
      for (int nf = 0; nf < 4; ++nf)                                         \
        acc[mf][nf] = __builtin_amdgcn_mfma_f32_16x16x32_bf16(af[mf], bf[nf], acc[mf][nf], 0, 0, 0); \
  } while (0)

  // IDIM/32 = 32 K-tiles. tile k lives in buf[k&1].
  G2_STAGE(0);                 // tile 0
  __syncthreads();
#pragma unroll 1
  for (int t = 0; t < 15; ++t) {
    G2_STAGE(1);               // tile 2t+1
    G2_COMPUTE(0);             // tile 2t
    __syncthreads();
    G2_STAGE(0);               // tile 2t+2
    G2_COMPUTE(1);             // tile 2t+1
    __syncthreads();
  }
  G2_STAGE(1);                 // tile 31
  G2_COMPUTE(0);               // tile 30
  __syncthreads();
  G2_COMPUTE(1);               // tile 31

#undef G2_STAGE
#undef G2_COMPUTE

  const int ncol = nt * 128 + wx * 64;
#pragma unroll
  for (int mf = 0; mf < 4; ++mf) {
    const int sbase = slot0 + wy * 64 + mf * 16 + (lane >> 4) * 4;
#pragma unroll
    for (int ri = 0; ri < 4; ++ri) {
      int s = sbase + ri;
      float w = bw[s];   // padded slots: garbage but finite; never combined
#pragma unroll
      for (int nf = 0; nf < 4; ++nf) {
        int c = ncol + nf * 16 + (lane & 15);
        y[(size_t)s * HDIM + c] = (__bf16)(acc[mf][nf][ri] * w);
      }
    }
  }
}

// ---------------------------------------------------------------------------
// out[t] = y[pos0[t]] + y[pos1[t]]
__global__ __launch_bounds__(256) void combine_k(
    const __bf16* __restrict__ y, const int* __restrict__ pos_of,
    float* __restrict__ out) {
  const int t  = blockIdx.x;
  const int c8 = threadIdx.x * 8;
  const int p0 = pos_of[t * 2 + 0];
  const int p1 = pos_of[t * 2 + 1];
  bf16x8 a = *(const bf16x8*)&y[(size_t)p0 * HDIM + c8];
  bf16x8 b = *(const bf16x8*)&y[(size_t)p1 * HDIM + c8];
  float4 o0, o1;
  o0.x = (float)a[0] + (float)b[0];  o0.y = (float)a[1] + (float)b[1];
  o0.z = (float)a[2] + (float)b[2];  o0.w = (float)a[3] + (float)b[3];
  o1.x = (float)a[4] + (float)b[4];  o1.y = (float)a[5] + (float)b[5];
  o1.z = (float)a[6] + (float)b[6];  o1.w = (float)a[7] + (float)b[7];
  float* op = out + (size_t)t * HDIM + c8;
  *(float4*)op = o0;
  *(float4*)(op + 4) = o1;
}

// ---------------------------------------------------------------------------
extern "C" void kernel_launch(void* const* d_in, const int* in_sizes, int n_in,
                              void* d_out, int out_size, void* d_ws, size_t ws_size,
                              hipStream_t stream) {
  (void)in_sizes; (void)n_in; (void)out_size; (void)ws_size;
  const float* x  = (const float*)d_in[0];
  const float* wg = (const float*)d_in[1];
  const float* w1 = (const float*)d_in[2];
  const float* w3 = (const float*)d_in[3];
  const float* w2 = (const float*)d_in[4];
  float* out = (float*)d_out;

  char* ws = (char*)d_ws;
  size_t off = 0;
  auto alloc = [&](size_t bytes) -> char* {
    char* p = ws + off;
    off += (bytes + 255) & ~(size_t)255;
    return p;
  };
  __bf16* xb      = (__bf16*)alloc((size_t)T_TOK * HDIM * 2);          // 33.5 MB
  __bf16* w1b     = (__bf16*)alloc((size_t)NEXP * IDIM * HDIM * 2);    // 33.5 MB
  __bf16* w3b     = (__bf16*)alloc((size_t)NEXP * IDIM * HDIM * 2);    // 33.5 MB
  __bf16* w2b     = (__bf16*)alloc((size_t)NEXP * HDIM * IDIM * 2);    // 33.5 MB
  __bf16* h       = (__bf16*)alloc((size_t)CAP * IDIM * 2);            // 35.7 MB
  __bf16* y       = (__bf16*)alloc((size_t)CAP * HDIM * 2);            // 71.3 MB
  int*    btok    = (int*)alloc((size_t)CAP * 4);
  float*  bw      = (float*)alloc((size_t)CAP * 4);
  int*    pos_of  = (int*)alloc((size_t)T_TOK * 2 * 4);
  int*    tok_idx = (int*)alloc((size_t)T_TOK * 2 * 4);
  float*  tok_w   = (float*)alloc((size_t)T_TOK * 2 * 4);
  int*    counts  = (int*)alloc(256);
  int*    ctr2    = (int*)alloc(256);
  int*    offp    = (int*)alloc(256);
  // total ws ~ 242 MB

  hipMemsetAsync(counts, 0, 768, stream);                 // counts+ctr2+offp

  const int n4w = NEXP * IDIM * HDIM / 4;
  cvt_k<<<2048, 256, 0, stream>>>(w1, w1b, n4w);
  cvt_k<<<2048, 256, 0, stream>>>(w3, w3b, n4w);
  cvt_k<<<2048, 256, 0, stream>>>(w2, w2b, n4w);

  logits_k<<<T_TOK / LTOK, 256, 0, stream>>>(x, wg, xb, tok_idx, tok_w);
  hist_k<<<T_TOK / 256, 256, 0, stream>>>(tok_idx, counts);
  offsets_k<<<1, 64, 0, stream>>>(counts, offp, ctr2);
  assign_k<<<T_TOK / 256, 256, 0, stream>>>(tok_idx, tok_w, offp, ctr2, btok, bw, pos_of);

  gemm1_k<<<dim3(IDIM / 128, NTILE), 256, 0, stream>>>(xb, w1b, w3b, h, btok, counts, offp);
  gemm2_k<<<dim3(HDIM / 128, NTILE), 256, 0, stream>>>(h, w2b, y, bw, offp);
  combine_k<<<T_TOK, 256, 0, stream>>>(y, pos_of, out);
}

// Round 2
// 699.834 us; speedup vs baseline: 1.1740x; 1.1740x over previous
//
#include <hip/hip_runtime.h>
#include <cstdint>
#include <cstddef>

// Problem constants (from setup_inputs)
#define T_TOK 8192
#define HDIM  2048
#define NEXP  8
#define IDIM  1024
#define CAP   18432         // 16384 assignments + 8*255 pad, rounded to 256
#define NTILE (CAP / 256)   // 72 padded slot-tiles max (256-row tiles)
#define LTOK  16            // tokens per logits block

typedef __attribute__((ext_vector_type(8))) __bf16 bf16x8;
typedef __attribute__((ext_vector_type(4))) __bf16 bf16x4;
typedef __attribute__((ext_vector_type(4))) float  f32x4;

// async global->LDS, 16B/lane. LDS dest = wave-uniform base + lane*16.
#define GLDS16(g, l)                                                        \
  __builtin_amdgcn_global_load_lds(                                         \
      (__attribute__((address_space(1))) void*)(g),                         \
      (__attribute__((address_space(3))) void*)(l), 16, 0, 0)

// ---------------------------------------------------------------------------
// fp32 -> bf16 bulk convert (w2)
__global__ __launch_bounds__(256) void cvt_k(const float* __restrict__ src,
                                             __bf16* __restrict__ dst, int n4) {
  int i = blockIdx.x * blockDim.x + threadIdx.x;
  int stride = gridDim.x * blockDim.x;
  for (; i < n4; i += stride) {
    float4 v = ((const float4*)src)[i];
    bf16x4 b;
    b[0] = (__bf16)v.x; b[1] = (__bf16)v.y; b[2] = (__bf16)v.z; b[3] = (__bf16)v.w;
    ((bf16x4*)dst)[i] = b;
  }
}

// fp32 -> bf16 convert of w1/w3 into interleaved wcat layout:
// wcat[e] row 32j+r (r<16) = w1[e] row 16j+r ; row 32j+16+r = w3[e] row 16j+r.
// Any aligned 256-row tile of wcat then alternates 16-row w1/w3 blocks, so in
// the MFMA fragment decomposition nf=0 frags are g and nf=1 frags are u for
// the SAME (slot, i) in the SAME lane -> SwiGLU fuses in-register.
__global__ __launch_bounds__(256) void cvt13_k(const float* __restrict__ src,
                                               __bf16* __restrict__ dst,
                                               int is_w3) {
  const int n4 = NEXP * IDIM * (HDIM / 4);
  int i = blockIdx.x * blockDim.x + threadIdx.x;
  int stride = gridDim.x * blockDim.x;
  for (; i < n4; i += stride) {
    int e   = i >> 19;            // IDIM*HDIM/4 = 2^19
    int rem = i & 524287;
    int r   = rem >> 9;           // HDIM/4 = 512
    int c4  = rem & 511;
    int wrow = ((r >> 4) << 5) + (r & 15) + (is_w3 << 4);
    float4 v = ((const float4*)src)[i];
    bf16x4 b;
    b[0] = (__bf16)v.x; b[1] = (__bf16)v.y; b[2] = (__bf16)v.z; b[3] = (__bf16)v.w;
    ((bf16x4*)dst)[((size_t)e * 2 * IDIM + wrow) * 512 + c4] = b;
  }
}

// ---------------------------------------------------------------------------
// Logits + top-2 (unchanged)
__global__ __launch_bounds__(256) void logits_k(
    const float* __restrict__ x, const float* __restrict__ wg,
    __bf16* __restrict__ xb, int* __restrict__ tok_idx,
    float* __restrict__ tok_w) {
  __shared__ float wgs[NEXP * HDIM];   // 64 KB
  {
    const float4* wg4 = (const float4*)wg;
    float4* wgs4 = (float4*)wgs;
    for (int i = threadIdx.x; i < NEXP * HDIM / 4; i += 256) wgs4[i] = wg4[i];
  }
  __syncthreads();

  const int wid  = threadIdx.x >> 6;
  const int lane = threadIdx.x & 63;

  for (int ti = 0; ti < LTOK / 4; ++ti) {
    const int t = blockIdx.x * LTOK + wid * (LTOK / 4) + ti;
    const float4* x4 = (const float4*)(x + (size_t)t * HDIM);
    bf16x4* xb4 = (bf16x4*)(xb + (size_t)t * HDIM);

    double acc[NEXP];
#pragma unroll
    for (int e = 0; e < NEXP; ++e) acc[e] = 0.0;

#pragma unroll
    for (int j = 0; j < 8; ++j) {
      int idx = j * 64 + lane;
      float4 xv = x4[idx];
      bf16x4 b;
      b[0] = (__bf16)xv.x; b[1] = (__bf16)xv.y; b[2] = (__bf16)xv.z; b[3] = (__bf16)xv.w;
      xb4[idx] = b;
#pragma unroll
      for (int e = 0; e < NEXP; ++e) {
        float4 wv = ((const float4*)(wgs + e * HDIM))[idx];
        acc[e] += (double)xv.x * wv.x + (double)xv.y * wv.y +
                  (double)xv.z * wv.z + (double)xv.w * wv.w;
      }
    }
#pragma unroll
    for (int off = 32; off > 0; off >>= 1)
#pragma unroll
      for (int e = 0; e < NEXP; ++e) acc[e] += __shfl_xor(acc[e], off, 64);

    if (lane == 0) {
      int i0 = 0; double m0 = acc[0];
      for (int e = 1; e < NEXP; ++e) if (acc[e] > m0) { m0 = acc[e]; i0 = e; }
      int i1 = -1; double m1 = -1e300;
      for (int e = 0; e < NEXP; ++e)
        if (e != i0 && acc[e] > m1) { m1 = acc[e]; i1 = e; }
      double p0 = 1.0 / (1.0 + exp(m1 - m0));
      tok_idx[t * 2 + 0] = i0;  tok_idx[t * 2 + 1] = i1;
      tok_w[t * 2 + 0] = (float)p0;
      tok_w[t * 2 + 1] = (float)(1.0 - p0);
    }
  }
}

// ---------------------------------------------------------------------------
__global__ __launch_bounds__(256) void hist_k(const int* __restrict__ tok_idx,
                                              int* __restrict__ counts) {
  __shared__ int h[NEXP];
  if (threadIdx.x < NEXP) h[threadIdx.x] = 0;
  __syncthreads();
  int t = blockIdx.x * blockDim.x + threadIdx.x;
  atomicAdd(&h[tok_idx[t * 2 + 0]], 1);
  atomicAdd(&h[tok_idx[t * 2 + 1]], 1);
  __syncthreads();
  if (threadIdx.x < NEXP) atomicAdd(&counts[threadIdx.x], h[threadIdx.x]);
}

// ---------------------------------------------------------------------------
// Padded (to 256) exclusive scan of counts.
__global__ void offsets_k(const int* __restrict__ counts, int* __restrict__ offp,
                          int* __restrict__ ctr2) {
  if (threadIdx.x == 0) {
    int off = 0;
    for (int e = 0; e < NEXP; ++e) { offp[e] = off; off += (counts[e] + 255) & ~255; }
    offp[NEXP] = off;
  }
  if (threadIdx.x < NEXP) ctr2[threadIdx.x] = 0;
}

// ---------------------------------------------------------------------------
__global__ __launch_bounds__(256) void assign_k(
    const int* __restrict__ tok_idx, const float* __restrict__ tok_w,
    const int* __restrict__ offp, int* __restrict__ ctr2,
    int* __restrict__ btok, float* __restrict__ bw, int* __restrict__ pos_of) {
  __shared__ int lcnt[NEXP], lbase[NEXP];
  if (threadIdx.x < NEXP) lcnt[threadIdx.x] = 0;
  __syncthreads();
  const int t  = blockIdx.x * blockDim.x + threadIdx.x;
  const int e0 = tok_idx[t * 2 + 0];
  const int e1 = tok_idx[t * 2 + 1];
  const int r0 = atomicAdd(&lcnt[e0], 1);
  const int r1 = atomicAdd(&lcnt[e1], 1);
  __syncthreads();
  if (threadIdx.x < NEXP)
    lbase[threadIdx.x] = atomicAdd(&ctr2[threadIdx.x], lcnt[threadIdx.x]);
  __syncthreads();
  int p0 = offp[e0] + lbase[e0] + r0;
  int p1 = offp[e1] + lbase[e1] + r1;
  btok[p0] = t;  bw[p0] = tok_w[t * 2 + 0];  pos_of[t * 2 + 0] = p0;
  btok[p1] = t;  bw[p1] = tok_w[t * 2 + 1];  pos_of[t * 2 + 1] = p1;
}

// ---------------------------------------------------------------------------
__device__ __forceinline__ int tile_expert(const int* offp, int slot0) {
  if (slot0 >= offp[NEXP]) return -1;
  int e = 0;
#pragma unroll
  for (int i = 1; i < NEXP; ++i) if (offp[i] <= slot0) e = i;
  return e;
}

// ===========================================================================
// 256x256 / BK=64 / 8-wave / 8-phase GEMM machinery (m201-style template).
//
// LDS images: A,B each 2 buf x 2 halves x (128 rows x 64 cols bf16 = 16KB).
// Half-tile image is SUBTILED: [8 subrows][2 subcols][16 rows][32 cols] with
// st_16x32 swizzle (byte ^= ((byte>>9)&1)<<5). global_load_lds writes the
// image LINEARLY (base + tid*16); the source address is pre-swizzled so data
// for swizzled positions lands linearly; ds_read applies the same XOR.
//
// Wave (wy 0..1, wx 0..3) owns 64 rows in EACH A-half x 32 cols in EACH
// B-half; phase p uses exactly halves (hA=p>>1, hB=p&1). Stage slots:
//   p0: B1(t+1)  p1: A1(t+1)  p2: A0(t+2)  p3: B0(t+2),  vmcnt(4) at p3
// => tile t+1 provably resident before its first read; 2 half-tiles in
// flight; vmcnt never drained to 0 in steady state (T4).
// ===========================================================================
#define BAR __builtin_amdgcn_s_barrier()
#define VMC(N) asm volatile("s_waitcnt vmcnt(" #N ")" ::: "memory")

#define STG(P0, P1, LB)                                                       \
  { GLDS16(P0, (LB) + tid * 8);                                               \
    GLDS16(P1, (LB) + 4096 + tid * 8);                                        \
    P0 += 64; P1 += 64; }

#define LOADA(BUF, HA)                                                        \
  { _Pragma("unroll") for (int mf = 0; mf < 4; ++mf)                          \
    _Pragma("unroll") for (int ks = 0; ks < 2; ++ks)                          \
      a[mf][ks] = *(const bf16x8*)&As[(BUF)*16384 + (HA)*8192 +               \
                                      ((wy*4 + mf)*2 + ks)*512 + laneAe]; }

#define LOADB(BUF, HB)                                                        \
  { _Pragma("unroll") for (int nf = 0; nf < 2; ++nf)                          \
    _Pragma("unroll") for (int ks = 0; ks < 2; ++ks)                          \
      b[nf][ks] = *(const bf16x8*)&Bs[(BUF)*16384 + (HB)*8192 +               \
                                      ((wx*2 + nf)*2 + ks)*512 + laneAe]; }

#define MFMAQ(HA, HB)                                                         \
  { __builtin_amdgcn_s_setprio(1);                                            \
    _Pragma("unroll") for (int mf = 0; mf < 4; ++mf)                          \
    _Pragma("unroll") for (int nf = 0; nf < 2; ++nf)                          \
    _Pragma("unroll") for (int ks = 0; ks < 2; ++ks)                          \
      acc[(HA)*4 + mf][(HB)*2 + nf] = __builtin_amdgcn_mfma_f32_16x16x32_bf16(\
          a[mf][ks], b[nf][ks], acc[(HA)*4 + mf][(HB)*2 + nf], 0, 0, 0);      \
    __builtin_amdgcn_s_setprio(0); }

#define FULLTILE(BUF, TC, NTK)                                                \
  { /* phase 0: hA=0,hB=0 */                                                  \
    LOADA(BUF, 0); LOADB(BUF, 0);                                             \
    if ((TC) + 1 < (NTK)) { STG(pB1a, pB1b, Bs + ((BUF)^1)*16384 + 8192); }   \
    BAR; MFMAQ(0, 0); BAR;                                                    \
    /* phase 1: hA=0,hB=1 */                                                  \
    LOADB(BUF, 1);                                                            \
    if ((TC) + 1 < (NTK)) { STG(pA1a, pA1b, As + ((BUF)^1)*16384 + 8192); }   \
    BAR; MFMAQ(0, 1); BAR;                                                    \
    /* phase 2: hA=1,hB=0 */                                                  \
    LOADA(BUF, 1); LOADB(BUF, 0);                                             \
    if ((TC) + 2 < (NTK)) { STG(pA0a, pA0b, As + (BUF)*16384); }              \
    BAR; MFMAQ(1, 0); BAR;                                                    \
    /* phase 3: hA=1,hB=1 */                                                  \
    LOADB(BUF, 1);                                                            \
    if ((TC) + 2 < (NTK)) { STG(pB0a, pB0b, Bs + (BUF)*16384); }              \
    BAR; MFMAQ(1, 1);                                                         \
    if ((TC) + 2 < (NTK))      { VMC(4); }                                    \
    else if ((TC) + 1 < (NTK)) { VMC(0); }                                    \
    BAR; }

// Per-thread staging decode (shared by all stage pointers):
//   q = L*8192 + ((tid*16) ^ (tid&32))  [pre-swizzled source position]
//   row  = (q>>11)*16 + ((q>>6)&15)          in [0,128)
//   colE = ((q>>10)&1)*32 + ((q&63)>>1)      in bf16 elements, [0,64)
// ds_read address (elements): hA*8192 + ((wy*4+mf)*2+ks)*512 + laneAe,
//   laneAe = frow*32 + (((lane>>4)*8) ^ ((frow&8)<<1))

// ---------------------------------------------------------------------------
// GEMM1: gathered X [256 x K2048] x wcat tile [256 x K] -> h = silu(g)*u
__global__ __launch_bounds__(512, 2) void gemm1_k(
    const __bf16* __restrict__ xb, const __bf16* __restrict__ wcat,
    __bf16* __restrict__ h, const int* __restrict__ btok,
    const int* __restrict__ counts, const int* __restrict__ offp) {
  const int mt    = blockIdx.y;
  const int slot0 = mt * 256;
  const int e     = tile_expert(offp, slot0);
  if (e < 0) return;
  const int cnt  = counts[e];
  const int base = offp[e];
  const int mrow = slot0 - base;
  const int nt   = blockIdx.x;            // 128 i-values per block

  __shared__ __align__(16) __bf16 As[32768];   // 64 KB
  __shared__ __align__(16) __bf16 Bs[32768];   // 64 KB

  const int tid  = threadIdx.x;
  const int lane = tid & 63;
  const int wid  = tid >> 6;
  const int wy   = wid >> 2;   // 0..1
  const int wx   = wid & 3;    // 0..3
  const int frow = lane & 15;
  const int laneAe = frow * 32 + (((lane >> 4) * 8) ^ ((frow & 8) << 1));

  int rowS[2], colE[2];
#pragma unroll
  for (int L = 0; L < 2; ++L) {
    int q = L * 8192 + ((tid * 16) ^ (tid & 32));
    rowS[L] = (q >> 11) * 16 + ((q >> 6) & 15);
    colE[L] = ((q >> 10) & 1) * 32 + ((q & 63) >> 1);
  }

  const __bf16 *pA0a, *pA0b, *pA1a, *pA1b;
  {
    int m, tok;
    m = mrow + rowS[0];       m = m < cnt ? m : cnt - 1; tok = btok[base + m];
    pA0a = xb + (size_t)tok * HDIM + colE[0];
    m = mrow + rowS[1];       m = m < cnt ? m : cnt - 1; tok = btok[base + m];
    pA0b = xb + (size_t)tok * HDIM + colE[1];
    m = mrow + 128 + rowS[0]; m = m < cnt ? m : cnt - 1; tok = btok[base + m];
    pA1a = xb + (size_t)tok * HDIM + colE[0];
    m = mrow + 128 + rowS[1]; m = m < cnt ? m : cnt - 1; tok = btok[base + m];
    pA1b = xb + (size_t)tok * HDIM + colE[1];
  }
  const __bf16* Bb = wcat + ((size_t)e * 2 * IDIM + nt * 256) * HDIM;
  const __bf16* pB0a = Bb + (size_t)rowS[0] * HDIM + colE[0];
  const __bf16* pB0b = Bb + (size_t)rowS[1] * HDIM + colE[1];
  const __bf16* pB1a = Bb + (size_t)(128 + rowS[0]) * HDIM + colE[0];
  const __bf16* pB1b = Bb + (size_t)(128 + rowS[1]) * HDIM + colE[1];

  f32x4 acc[8][4] = {};
  bf16x8 a[4][2], b[2][2];

  // prologue: tile0 (all 4 halves) + tile1 (A0, B0)
  STG(pA0a, pA0b, As + 0);
  STG(pA1a, pA1b, As + 8192);
  STG(pB0a, pB0b, Bs + 0);
  STG(pB1a, pB1b, Bs + 8192);
  STG(pA0a, pA0b, As + 16384);
  STG(pB0a, pB0b, Bs + 16384);
  VMC(4);
  BAR;

#pragma unroll 1
  for (int t = 0; t < HDIM / 64; t += 2) {
    FULLTILE(0, t, HDIM / 64);
    FULLTILE(1, t + 1, HDIM / 64);
  }

  // epilogue: SwiGLU in-register (nf=0 -> g, nf=1 -> u for same (s,i))
  const int l4 = (lane >> 4) * 4;
#pragma unroll
  for (int hA = 0; hA < 2; ++hA)
#pragma unroll
    for (int mf = 0; mf < 4; ++mf) {
      const int srow = slot0 + hA * 128 + wy * 64 + mf * 16 + l4;
#pragma unroll
      for (int hB = 0; hB < 2; ++hB) {
        const int ic = nt * 128 + hB * 64 + wx * 16 + frow;
#pragma unroll
        for (int ri = 0; ri < 4; ++ri) {
          const int s = srow + ri;
          if (s - base < cnt) {
            float g = acc[hA * 4 + mf][hB * 2 + 0][ri];
            float u = acc[hA * 4 + mf][hB * 2 + 1][ri];
            float sv = g / (1.0f + __expf(-g)) * u;
            h[(size_t)s * IDIM + ic] = (__bf16)sv;
          }
        }
      }
    }
}

// ---------------------------------------------------------------------------
// GEMM2: h [256 x K1024] x w2 tile [256 x K1024] -> y[slot] = w * acc
__global__ __launch_bounds__(512, 2) void gemm2_k(
    const __bf16* __restrict__ hin, const __bf16* __restrict__ w2b,
    __bf16* __restrict__ y, const float* __restrict__ bw,
    const int* __restrict__ offp) {
  const int mt    = blockIdx.y;
  const int slot0 = mt * 256;
  const int e     = tile_expert(offp, slot0);
  if (e < 0) return;
  const int nt = blockIdx.x;     // 256 H-cols per block

  __shared__ __align__(16) __bf16 As[32768];
  __shared__ __align__(16) __bf16 Bs[32768];

  const int tid  = threadIdx.x;
  const int lane = tid & 63;
  const int wid  = tid >> 6;
  const int wy   = wid >> 2;
  const int wx   = wid & 3;
  const int frow = lane & 15;
  const int laneAe = frow * 32 + (((lane >> 4) * 8) ^ ((frow & 8) << 1));

  int rowS[2], colE[2];
#pragma unroll
  for (int L = 0; L < 2; ++L) {
    int q = L * 8192 + ((tid * 16) ^ (tid & 32));
    rowS[L] = (q >> 11) * 16 + ((q >> 6) & 15);
    colE[L] = ((q >> 10) & 1) * 32 + ((q & 63) >> 1);
  }

  const __bf16* pA0a = hin + (size_t)(slot0 + rowS[0]) * IDIM + colE[0];
  const __bf16* pA0b = hin + (size_t)(slot0 + rowS[1]) * IDIM + colE[1];
  const __bf16* pA1a = hin + (size_t)(slot0 + 128 + rowS[0]) * IDIM + colE[0];
  const __bf16* pA1b = hin + (size_t)(slot0 + 128 + rowS[1]) * IDIM + colE[1];
  const __bf16* Bb = w2b + ((size_t)e * HDIM + nt * 256) * IDIM;
  const __bf16* pB0a = Bb + (size_t)rowS[0] * IDIM + colE[0];
  const __bf16* pB0b = Bb + (size_t)rowS[1] * IDIM + colE[1];
  const __bf16* pB1a = Bb + (size_t)(128 + rowS[0]) * IDIM + colE[0];
  const __bf16* pB1b = Bb + (size_t)(128 + rowS[1]) * IDIM + colE[1];

  f32x4 acc[8][4] = {};
  bf16x8 a[4][2], b[2][2];

  STG(pA0a, pA0b, As + 0);
  STG(pA1a, pA1b, As + 8192);
  STG(pB0a, pB0b, Bs + 0);
  STG(pB1a, pB1b, Bs + 8192);
  STG(pA0a, pA0b, As + 16384);
  STG(pB0a, pB0b, Bs + 16384);
  VMC(4);
  BAR;

#pragma unroll 1
  for (int t = 0; t < IDIM / 64; t += 2) {
    FULLTILE(0, t, IDIM / 64);
    FULLTILE(1, t + 1, IDIM / 64);
  }

  const int l4 = (lane >> 4) * 4;
#pragma unroll
  for (int hA = 0; hA < 2; ++hA)
#pragma unroll
    for (int mf = 0; mf < 4; ++mf) {
      const int srow = slot0 + hA * 128 + wy * 64 + mf * 16 + l4;
#pragma unroll
      for (int ri = 0; ri < 4; ++ri) {
        const int s = srow + ri;
        const float w = bw[s];   // padded slots: garbage but never combined
#pragma unroll
        for (int hB = 0; hB < 2; ++hB)
#pragma unroll
          for (int nf = 0; nf < 2; ++nf) {
            const int c = nt * 256 + hB * 128 + wx * 32 + nf * 16 + frow;
            y[(size_t)s * HDIM + c] = (__bf16)(acc[hA * 4 + mf][hB * 2 + nf][ri] * w);
          }
      }
    }
}

// ---------------------------------------------------------------------------
// out[t] = y[pos0[t]] + y[pos1[t]]
__global__ __launch_bounds__(256) void combine_k(
    const __bf16* __restrict__ y, const int* __restrict__ pos_of,
    float* __restrict__ out) {
  const int t  = blockIdx.x;
  const int c8 = threadIdx.x * 8;
  const int p0 = pos_of[t * 2 + 0];
  const int p1 = pos_of[t * 2 + 1];
  bf16x8 a = *(const bf16x8*)&y[(size_t)p0 * HDIM + c8];
  bf16x8 b = *(const bf16x8*)&y[(size_t)p1 * HDIM + c8];
  float4 o0, o1;
  o0.x = (float)a[0] + (float)b[0];  o0.y = (float)a[1] + (float)b[1];
  o0.z = (float)a[2] + (float)b[2];  o0.w = (float)a[3] + (float)b[3];
  o1.x = (float)a[4] + (float)b[4];  o1.y = (float)a[5] + (float)b[5];
  o1.z = (float)a[6] + (float)b[6];  o1.w = (float)a[7] + (float)b[7];
  float* op = out + (size_t)t * HDIM + c8;
  *(float4*)op = o0;
  *(float4*)(op + 4) = o1;
}

// ---------------------------------------------------------------------------
extern "C" void kernel_launch(void* const* d_in, const int* in_sizes, int n_in,
                              void* d_out, int out_size, void* d_ws, size_t ws_size,
                              hipStream_t stream) {
  (void)in_sizes; (void)n_in; (void)out_size; (void)ws_size;
  const float* x  = (const float*)d_in[0];
  const float* wg = (const float*)d_in[1];
  const float* w1 = (const float*)d_in[2];
  const float* w3 = (const float*)d_in[3];
  const float* w2 = (const float*)d_in[4];
  float* out = (float*)d_out;

  char* ws = (char*)d_ws;
  size_t off = 0;
  auto alloc = [&](size_t bytes) -> char* {
    char* p = ws + off;
    off += (bytes + 255) & ~(size_t)255;
    return p;
  };
  // y (75.5 MB) aliases xb+wcat (100.7 MB): xb/wcat are dead before gemm2
  // writes y (stream-ordered). Total ws use ~173 MB.
  __bf16* xb      = (__bf16*)alloc((size_t)T_TOK * HDIM * 2);             // 33.5 MB
  __bf16* wcat    = (__bf16*)alloc((size_t)NEXP * 2 * IDIM * HDIM * 2);   // 67.1 MB
  __bf16* w2b     = (__bf16*)alloc((size_t)NEXP * HDIM * IDIM * 2);       // 33.5 MB
  __bf16* h       = (__bf16*)alloc((size_t)CAP * IDIM * 2);               // 37.7 MB
  int*    btok    = (int*)alloc((size_t)CAP * 4);
  float*  bw      = (float*)alloc((size_t)CAP * 4);
  int*    pos_of  = (int*)alloc((size_t)T_TOK * 2 * 4);
  int*    tok_idx = (int*)alloc((size_t)T_TOK * 2 * 4);
  float*  tok_w   = (float*)alloc((size_t)T_TOK * 2 * 4);
  int*    counts  = (int*)alloc(256);
  int*    ctr2    = (int*)alloc(256);
  int*    offp    = (int*)alloc(256);
  __bf16* y       = (__bf16*)ws;                                          // alias

  hipMemsetAsync(counts, 0, 768, stream);                 // counts+ctr2+offp

  const int n4w = NEXP * IDIM * HDIM / 4;
  cvt13_k<<<2048, 256, 0, stream>>>(w1, wcat, 0);
  cvt13_k<<<2048, 256, 0, stream>>>(w3, wcat, 1);
  cvt_k<<<2048, 256, 0, stream>>>(w2, w2b, n4w);

  logits_k<<<T_TOK / LTOK, 256, 0, stream>>>(x, wg, xb, tok_idx, tok_w);
  hist_k<<<T_TOK / 256, 256, 0, stream>>>(tok_idx, counts);
  offsets_k<<<1, 64, 0, stream>>>(counts, offp, ctr2);
  assign_k<<<T_TOK / 256, 256, 0, stream>>>(tok_idx, tok_w, offp, ctr2, btok, bw, pos_of);

  gemm1_k<<<dim3(IDIM / 128, NTILE), 512, 0, stream>>>(xb, wcat, h, btok, counts, offp);
  gemm2_k<<<dim3(HDIM / 256, NTILE), 512, 0, stream>>>(h, w2b, y, bw, offp);
  combine_k<<<T_TOK, 256, 0, stream>>>(y, pos_of, out);
}